// Round 15
// baseline (213.398 us; speedup 1.0000x reference)
//
#include <hip/hip_runtime.h>
#include <math.h>

// GATv2Regressor: N=100k nodes, E=1.6M edges (+N self-loops), F=128, C=32, H1=2, G=64.
// CSR-by-dst GAT layers (no-max softmax via exp2, packed-f32 (v_pk_*) channel math on
// bf16-pair lanes, 2-DPP quad reductions, load-ahead gathers, bf16 tables);
// CSR via bucket partition; dense via B-resident bf16 MFMA GEMMs; split pooling.

constexpr float LOG2E = 1.44269504088896f;

typedef short bf16x8 __attribute__((ext_vector_type(8)));   // 8 bf16 (4 VGPRs)
typedef float f32x4  __attribute__((ext_vector_type(4)));   // MFMA accumulator
typedef float f32x2  __attribute__((ext_vector_type(2)));   // packed-f32 pair (v_pk_*)

// DPP quad_perm: xor1 = 0xB1, xor2 = 0x4E.  REDUCE4 = sum within aligned 4-lane quads.
#define DPP_ADD(v, ctrl)                                                             \
  do {                                                                               \
    int _t = __builtin_amdgcn_update_dpp(0, __float_as_int(v), (ctrl), 0xF, 0xF, true); \
    (v) = (v) + __int_as_float(_t);                                                  \
  } while (0)
#define REDUCE4(v) do { DPP_ADD(v, 0xB1); DPP_ADD(v, 0x4E); } while (0)

__device__ __forceinline__ unsigned short f2bf(float f) {   // RNE f32 -> bf16
  unsigned u = __float_as_uint(f);
  return (unsigned short)((u + 0x7FFFu + ((u >> 16) & 1u)) >> 16);
}
__device__ __forceinline__ f32x2 bfPAIR(unsigned u) {       // u32 = 2 bf16 -> f32x2
  f32x2 r;
  r.x = __uint_as_float(u << 16);
  r.y = __uint_as_float(u & 0xFFFF0000u);
  return r;
}

// ---------------- W transpose (both layers in one launch) ----------------
__global__ __launch_bounds__(256) void wtrans_kernel(
    const float* __restrict__ Wl1, const float* __restrict__ Wr1, unsigned short* __restrict__ WT1,
    const float* __restrict__ Wl2, const float* __restrict__ Wr2, unsigned short* __restrict__ WT2)
{
  int g = blockIdx.x * 256 + threadIdx.x;
  int g1 = 128 * 16;
  int K, NHALF, col, kb;
  const float *Wl, *Wr; unsigned short* WT;
  if (g < g1) { K = 128; NHALF = 64; Wl = Wl1; Wr = Wr1; WT = WT1; }
  else        { g -= g1; if (g >= 64 * 8) return; K = 64; NHALF = 32; Wl = Wl2; Wr = Wr2; WT = WT2; }
  col = g / (K / 8);
  kb  = (g % (K / 8)) * 8;
  const float* W = (col < NHALF) ? Wl : Wr;
  int c = (col < NHALF) ? col : col - NHALF;
  float v[8];
#pragma unroll
  for (int i = 0; i < 8; ++i) v[i] = W[(size_t)(kb + i) * NHALF + c];
  ushort4 h0, h1;
  h0.x = f2bf(v[0]); h0.y = f2bf(v[1]); h0.z = f2bf(v[2]); h0.w = f2bf(v[3]);
  h1.x = f2bf(v[4]); h1.y = f2bf(v[5]); h1.z = f2bf(v[6]); h1.w = f2bf(v[7]);
  *(ushort4*)&WT[(size_t)col * K + kb]     = h0;
  *(ushort4*)&WT[(size_t)col * K + kb + 4] = h1;
}

// ---------------- dense: bf16 MFMA dual-weight GEMM, B-resident ----------------
template<int K, int NHALF, int WAVES>
__global__ __launch_bounds__(WAVES * 64) void mm_mfma_kernel(const float* __restrict__ x,
    const unsigned short* __restrict__ WT,
    const float* __restrict__ bl, const float* __restrict__ br,
    unsigned short* __restrict__ outl, float* __restrict__ outr, int n)
{
  constexpr int KC = K / 32;
  constexpr int NT_THREADS = WAVES * 64;
  __shared__ unsigned short xs[64 * K];
  const int t = threadIdx.x;
  const int rowbase = blockIdx.x * 64;
  const int w = t >> 6, l = t & 63;
  const int bcol = w * 16 + (l & 15);
  const int kgrp = (l >> 4) * 8;

  bf16x8 bfr[KC];
#pragma unroll
  for (int kc = 0; kc < KC; ++kc)
    bfr[kc] = *(const bf16x8*)&WT[(size_t)bcol * K + kc * 32 + kgrp];

  constexpr int GPT = (64 * K / 8) / NT_THREADS;
#pragma unroll
  for (int g = 0; g < GPT; ++g) {
    int idx = t + g * NT_THREADS;
    int row = idx / (K / 8);
    int kb  = (idx % (K / 8)) * 8;
    int grow = rowbase + row;
    float4 a0 = make_float4(0.f, 0.f, 0.f, 0.f), a1 = a0;
    if (grow < n) {
      a0 = *(const float4*)&x[(size_t)grow * K + kb];
      a1 = *(const float4*)&x[(size_t)grow * K + kb + 4];
    }
    ushort4 h0, h1;
    h0.x = f2bf(a0.x); h0.y = f2bf(a0.y); h0.z = f2bf(a0.z); h0.w = f2bf(a0.w);
    h1.x = f2bf(a1.x); h1.y = f2bf(a1.y); h1.z = f2bf(a1.z); h1.w = f2bf(a1.w);
    int ksw = kb ^ ((row & 7) << 3);
    *(ushort4*)&xs[row * K + ksw]     = h0;
    *(ushort4*)&xs[row * K + ksw + 4] = h1;
  }
  __syncthreads();

  f32x4 zero = {0.f, 0.f, 0.f, 0.f};
  f32x4 acc[4];
#pragma unroll
  for (int i = 0; i < 4; ++i) acc[i] = zero;

#pragma unroll
  for (int rt = 0; rt < 4; ++rt) {
    int arow = rt * 16 + (l & 15);
    int asw  = (arow & 7) << 3;
#pragma unroll
    for (int kc = 0; kc < KC; ++kc) {
      bf16x8 a = *(const bf16x8*)&xs[arow * K + ((kc * 32 + kgrp) ^ asw)];
      acc[rt] = __builtin_amdgcn_mfma_f32_16x16x32_bf16(a, bfr[kc], acc[rt], 0, 0, 0);
    }
  }

  const bool isl = bcol < NHALF;
  const int col = isl ? bcol : bcol - NHALF;
  const float bb = isl ? bl[col] : br[col];
#pragma unroll
  for (int rt = 0; rt < 4; ++rt) {
    int r0 = rowbase + rt * 16 + (l >> 4) * 4;
#pragma unroll
    for (int j = 0; j < 4; ++j) {
      int row = r0 + j;
      if (row < n) {
        float v = acc[rt][j] + bb;
        if (isl) outl[(size_t)row * NHALF + col] = f2bf(v);
        else     outr[(size_t)row * NHALF + col] = v;
      }
    }
  }
}

// gate[n] = relu(h2 @ Wg1 + bg1) @ Wg2 + bg2 (fused, thread-per-row)
__global__ __launch_bounds__(256) void gate_kernel(const float* __restrict__ h2,
    const float* __restrict__ Wg1, const float* __restrict__ bg1,
    const float* __restrict__ Wg2, const float* __restrict__ bg2,
    float* __restrict__ gate, int n)
{
  int row = blockIdx.x * 256 + threadIdx.x;
  int rr = (row < n) ? row : 0;
  const float* hp = h2 + (size_t)rr * 32;
  float acc[32];
#pragma unroll
  for (int c = 0; c < 32; ++c) acc[c] = 0.f;
  for (int k0 = 0; k0 < 32; k0 += 8) {
    float4 a0 = *(const float4*)(hp + k0 + 0);
    float4 a1 = *(const float4*)(hp + k0 + 4);
    float xk[8];
    xk[0]=a0.x; xk[1]=a0.y; xk[2]=a0.z; xk[3]=a0.w;
    xk[4]=a1.x; xk[5]=a1.y; xk[6]=a1.z; xk[7]=a1.w;
#pragma unroll
    for (int kk = 0; kk < 8; ++kk) {
      const float* wv = Wg1 + (size_t)(k0 + kk) * 32;
#pragma unroll
      for (int c = 0; c < 32; ++c) acc[c] = fmaf(xk[kk], wv[c], acc[c]);
    }
  }
  if (row < n) {
    float g = 0.f;
#pragma unroll
    for (int c = 0; c < 32; ++c)
      g = fmaf(fmaxf(acc[c] + bg1[c], 0.f), Wg2[c], g);
    gate[row] = g + bg2[0];
  }
}

// ---------------- CSR build via bucket partition (256 dsts/bucket) ----------------
__global__ __launch_bounds__(256) void bucket_hist_kernel(const int* __restrict__ ei,
    int* __restrict__ buk_cnt, int E, int nbuk)
{
  __shared__ int h[512];
  for (int b = threadIdx.x; b < 512; b += 256) h[b] = 0;
  __syncthreads();
  int total = gridDim.x * 1024;
  for (int i = (blockIdx.x * 256 + threadIdx.x) * 4; i < E; i += total) {
    if (i + 3 < E) {
      int4 d = *(const int4*)&ei[E + i];
      atomicAdd(&h[((unsigned)d.x) >> 8], 1);
      atomicAdd(&h[((unsigned)d.y) >> 8], 1);
      atomicAdd(&h[((unsigned)d.z) >> 8], 1);
      atomicAdd(&h[((unsigned)d.w) >> 8], 1);
    } else {
      for (int j = i; j < E; ++j) atomicAdd(&h[((unsigned)ei[E + j]) >> 8], 1);
    }
  }
  __syncthreads();
  for (int b = threadIdx.x; b < nbuk; b += 256)
    if (h[b]) atomicAdd(&buk_cnt[b], h[b]);
}

__global__ __launch_bounds__(512) void scan_buckets_kernel(const int* __restrict__ buk_cnt,
    int* __restrict__ sbuk_off, int* __restrict__ buk_run, int nbuk, int E)
{
  __shared__ int lds[512];
  int t = threadIdx.x;
  int v = (t < nbuk) ? buk_cnt[t] : 0;
  lds[t] = v; __syncthreads();
  for (int off = 1; off < 512; off <<= 1) {
    int x = (t >= off) ? lds[t - off] : 0;
    __syncthreads();
    lds[t] += x;
    __syncthreads();
  }
  int excl = lds[t] - v;
  if (t < nbuk) { sbuk_off[t] = excl; buk_run[t] = excl; }
  if (t == nbuk) sbuk_off[t] = E;
}

// packed u32: src (17 bits) | dstlo (8 bits) << 17
__global__ __launch_bounds__(256) void partition_kernel(const int* __restrict__ ei,
    int* __restrict__ buk_run, unsigned* __restrict__ scratch, int E, int nbuk)
{
  __shared__ int lcnt[512];
  __shared__ int lbase[512];
  int t = threadIdx.x;
  for (int b = t; b < 512; b += 256) lcnt[b] = 0;
  __syncthreads();
  int chunk = ((E + gridDim.x - 1) / gridDim.x + 3) & ~3;
  int s = blockIdx.x * chunk, e = min(E, s + chunk);
  for (int i = s + t * 4; i < e; i += 1024) {
    if (i + 3 < e) {
      int4 d = *(const int4*)&ei[E + i];
      atomicAdd(&lcnt[((unsigned)d.x) >> 8], 1);
      atomicAdd(&lcnt[((unsigned)d.y) >> 8], 1);
      atomicAdd(&lcnt[((unsigned)d.z) >> 8], 1);
      atomicAdd(&lcnt[((unsigned)d.w) >> 8], 1);
    } else {
      for (int j = i; j < e; ++j) atomicAdd(&lcnt[((unsigned)ei[E + j]) >> 8], 1);
    }
  }
  __syncthreads();
  for (int b = t; b < nbuk; b += 256) {
    int c = lcnt[b];
    lbase[b] = c ? atomicAdd(&buk_run[b], c) : 0;
    lcnt[b] = 0;
  }
  __syncthreads();
  for (int i = s + t * 4; i < e; i += 1024) {
    if (i + 3 < e) {
      int4 sv = *(const int4*)&ei[i];
      int4 dv = *(const int4*)&ei[E + i];
#define SCAT(SS, DD) { int b = ((unsigned)(DD)) >> 8;                        \
      int r = atomicAdd(&lcnt[b], 1);                                        \
      scratch[lbase[b] + r] = (unsigned)(SS) | ((((unsigned)(DD)) & 255u) << 17); }
      SCAT(sv.x, dv.x) SCAT(sv.y, dv.y) SCAT(sv.z, dv.z) SCAT(sv.w, dv.w)
    } else {
      for (int j = i; j < e; ++j) {
        int ss = ei[j]; unsigned dd = (unsigned)ei[E + j];
        SCAT(ss, dd)
      }
#undef SCAT
    }
  }
}

__global__ __launch_bounds__(256) void bucket_fill_kernel(const unsigned* __restrict__ scratch,
    const int* __restrict__ sbuk_off, int* __restrict__ row_ptr,
    int* __restrict__ csr_src, int n, int nbuk)
{
  __shared__ int lcnt[256], sexcl[256], cnt2[256];
  int b = blockIdx.x, t = threadIdx.x;
  int dst0 = b << 8;
  int ndst = min(256, n - dst0);
  int s = sbuk_off[b], e = sbuk_off[b + 1];
  int base = s + dst0;
  lcnt[t] = (t < ndst) ? 1 : 0;   // +1 self-loop per dst
  __syncthreads();
  for (int i = s + t; i < e; i += 256)
    atomicAdd(&lcnt[scratch[i] >> 17], 1);
  __syncthreads();
  int c0 = lcnt[t];
  for (int off = 1; off < 256; off <<= 1) {
    int x = (t >= off) ? lcnt[t - off] : 0;
    __syncthreads();
    lcnt[t] += x;
    __syncthreads();
  }
  int ex = lcnt[t] - c0;
  sexcl[t] = ex;
  cnt2[t] = 1;
  if (t < ndst) {
    row_ptr[dst0 + t] = base + ex;
    csr_src[base + ex] = dst0 + t;        // self-loop in slot 0
  }
  if (b == nbuk - 1 && t == 0) row_ptr[n] = sbuk_off[nbuk] + n;
  __syncthreads();
  for (int i = s + t; i < e; i += 256) {
    unsigned u = scratch[i];
    int dl = u >> 17;
    int src = u & 0x1FFFF;
    int pos = base + sexcl[dl] + atomicAdd(&cnt2[dl], 1);
    csr_src[pos] = src;
  }
}

// ---------------- GATv2 layer 1: heads=2, ch=32; one wave/dst, 8 edges/iter ----------------
// 8 lanes/edge (g8 = l>>3); lane q = l&7 owns channels q*8..q*8+7 as 4 f32x2 pairs
// (packed-f32 math). leaky(t)*att*log2e folded; p = exp2(v).
__global__ __launch_bounds__(256) void gat1_kernel(const unsigned short* __restrict__ xl,
    const float* __restrict__ xr, const int* __restrict__ row_ptr,
    const int* __restrict__ csr_src, const float* __restrict__ att,
    const float* __restrict__ bias, float* __restrict__ hout, int n)
{
  int wid = (blockIdx.x * 256 + threadIdx.x) >> 6;
  if (wid >= n) return;
  wid = __builtin_amdgcn_readfirstlane(wid);
  int l = threadIdx.x & 63;
  int g8 = l >> 3;
  int q = l & 7;
  f32x2 xr2[4], a62[4], a42[4];
  {
    float4 x0 = *(const float4*)&xr[(size_t)wid * 64 + q * 8];
    float4 x1 = *(const float4*)&xr[(size_t)wid * 64 + q * 8 + 4];
    float4 c0 = *(const float4*)&att[q * 8];
    float4 c1 = *(const float4*)&att[q * 8 + 4];
    xr2[0] = f32x2{x0.x, x0.y}; xr2[1] = f32x2{x0.z, x0.w};
    xr2[2] = f32x2{x1.x, x1.y}; xr2[3] = f32x2{x1.z, x1.w};
    f32x2 av[4];
    av[0] = f32x2{c0.x, c0.y}; av[1] = f32x2{c0.z, c0.w};
    av[2] = f32x2{c1.x, c1.y}; av[3] = f32x2{c1.z, c1.w};
#pragma unroll
    for (int i = 0; i < 4; ++i) {
      a62[i] = av[i] * (0.6f * LOG2E);
      a42[i] = av[i] * (0.4f * LOG2E);
    }
  }
  int s = row_ptr[wid], e = row_ptr[wid + 1];
  f32x2 acc2[4];
#pragma unroll
  for (int i = 0; i < 4; ++i) acc2[i] = f32x2{0.f, 0.f};
  float d = 0.f;

#define LOAD1(CB, hv) {                                                       \
    int src_ = csr_src[min((CB) + g8, e - 1)];                                \
    hv = *(const int4*)&xl[(size_t)src_ * 64 + q * 8]; }

  int4 cur;
  LOAD1(s, cur)
  for (int cb = s; cb < e; cb += 8) {
    int4 nxt;
    LOAD1(min(cb + 8, e - 1), nxt)       // load-ahead (clamped, safe)
    f32x2 xc2[4];
    xc2[0] = bfPAIR((unsigned)cur.x); xc2[1] = bfPAIR((unsigned)cur.y);
    xc2[2] = bfPAIR((unsigned)cur.z); xc2[3] = bfPAIR((unsigned)cur.w);
    f32x2 v2 = f32x2{0.f, 0.f};
#pragma unroll
    for (int i = 0; i < 4; ++i) {
      f32x2 t = xc2[i] + xr2[i];          // v_pk_add_f32
      v2 = t * a62[i] + v2;               // v_pk_fma_f32 (contract)
      f32x2 at; at.x = fabsf(t.x); at.y = fabsf(t.y);
      v2 = at * a42[i] + v2;              // v_pk_fma_f32, abs as modifier
    }
    float v = v2.x + v2.y;
    REDUCE4(v);                           // per-head logit (4-lane quads)
    float p = __builtin_amdgcn_exp2f(v);
    p = (cb + g8 < e) ? p : 0.f;
    d += p;
    f32x2 p2 = f32x2{p, p};
#pragma unroll
    for (int i = 0; i < 4; ++i) acc2[i] = p2 * xc2[i] + acc2[i];   // v_pk_fma_f32
    cur = nxt;
  }
#undef LOAD1
  float acc[8];
#pragma unroll
  for (int i = 0; i < 4; ++i) { acc[2 * i] = acc2[i].x; acc[2 * i + 1] = acc2[i].y; }
#pragma unroll
  for (int i = 0; i < 8; ++i) {
    acc[i] += __shfl_xor(acc[i], 8);
    acc[i] += __shfl_xor(acc[i], 16);
    acc[i] += __shfl_xor(acc[i], 32);
  }
  d += __shfl_xor(d, 8); d += __shfl_xor(d, 16); d += __shfl_xor(d, 32);
  if (g8 == 0) {
    float inv = 1.f / (d + 1e-16f);
    float4 b0 = *(const float4*)&bias[q * 8];
    float4 b1 = *(const float4*)&bias[q * 8 + 4];
    float4 o0, o1;
    o0.x = fmaxf(fmaf(acc[0], inv, b0.x), 0.f);
    o0.y = fmaxf(fmaf(acc[1], inv, b0.y), 0.f);
    o0.z = fmaxf(fmaf(acc[2], inv, b0.z), 0.f);
    o0.w = fmaxf(fmaf(acc[3], inv, b0.w), 0.f);
    o1.x = fmaxf(fmaf(acc[4], inv, b1.x), 0.f);
    o1.y = fmaxf(fmaf(acc[5], inv, b1.y), 0.f);
    o1.z = fmaxf(fmaf(acc[6], inv, b1.z), 0.f);
    o1.w = fmaxf(fmaf(acc[7], inv, b1.w), 0.f);
    *(float4*)&hout[(size_t)wid * 64 + q * 8]     = o0;
    *(float4*)&hout[(size_t)wid * 64 + q * 8 + 4] = o1;
  }
}

// ---------------- GATv2 layer 2: heads=1, ch=32; one wave/dst, 16 edges/iter ----------------
// 4 lanes/edge (g16 = l>>2); lane q = l&3 owns channels q*8..q*8+7 as 4 f32x2 pairs.
__global__ __launch_bounds__(256) void gat2_kernel(const unsigned short* __restrict__ xl,
    const float* __restrict__ xr, const int* __restrict__ row_ptr,
    const int* __restrict__ csr_src, const float* __restrict__ att,
    const float* __restrict__ bias, float* __restrict__ hout, int n)
{
  int wid = (blockIdx.x * 256 + threadIdx.x) >> 6;
  if (wid >= n) return;
  wid = __builtin_amdgcn_readfirstlane(wid);
  int l = threadIdx.x & 63;
  int g16 = l >> 2;
  int q = l & 3;
  f32x2 xr2[4], a62[4], a42[4];
  {
    float4 x0 = *(const float4*)&xr[(size_t)wid * 32 + q * 8];
    float4 x1 = *(const float4*)&xr[(size_t)wid * 32 + q * 8 + 4];
    float4 c0 = *(const float4*)&att[q * 8];
    float4 c1 = *(const float4*)&att[q * 8 + 4];
    xr2[0] = f32x2{x0.x, x0.y}; xr2[1] = f32x2{x0.z, x0.w};
    xr2[2] = f32x2{x1.x, x1.y}; xr2[3] = f32x2{x1.z, x1.w};
    f32x2 av[4];
    av[0] = f32x2{c0.x, c0.y}; av[1] = f32x2{c0.z, c0.w};
    av[2] = f32x2{c1.x, c1.y}; av[3] = f32x2{c1.z, c1.w};
#pragma unroll
    for (int i = 0; i < 4; ++i) {
      a62[i] = av[i] * (0.6f * LOG2E);
      a42[i] = av[i] * (0.4f * LOG2E);
    }
  }
  int s = row_ptr[wid], e = row_ptr[wid + 1];
  int deg = e - s;
  f32x2 acc2[4];
#pragma unroll
  for (int i = 0; i < 4; ++i) acc2[i] = f32x2{0.f, 0.f};
  float d = 0.f;

#define LOAD2(I0, hv) {                                                       \
    int src_ = csr_src[s + min((I0) + g16, deg - 1)];                         \
    hv = *(const int4*)&xl[(size_t)src_ * 32 + q * 8]; }

  int4 cur;
  LOAD2(0, cur)
  for (int i0 = 0; i0 < deg; i0 += 16) {
    int4 nxt;
    LOAD2(min(i0 + 16, deg - 1), nxt)
    f32x2 xc2[4];
    xc2[0] = bfPAIR((unsigned)cur.x); xc2[1] = bfPAIR((unsigned)cur.y);
    xc2[2] = bfPAIR((unsigned)cur.z); xc2[3] = bfPAIR((unsigned)cur.w);
    f32x2 v2 = f32x2{0.f, 0.f};
#pragma unroll
    for (int i = 0; i < 4; ++i) {
      f32x2 t = xc2[i] + xr2[i];
      v2 = t * a62[i] + v2;
      f32x2 at; at.x = fabsf(t.x); at.y = fabsf(t.y);
      v2 = at * a42[i] + v2;
    }
    float v = v2.x + v2.y;
    REDUCE4(v);                           // full logit (4 lanes per edge)
    float p = __builtin_amdgcn_exp2f(v);
    p = (i0 + g16 < deg) ? p : 0.f;
    d += p;
    f32x2 p2 = f32x2{p, p};
#pragma unroll
    for (int i = 0; i < 4; ++i) acc2[i] = p2 * xc2[i] + acc2[i];
    cur = nxt;
  }
#undef LOAD2
  float acc[8];
#pragma unroll
  for (int i = 0; i < 4; ++i) { acc[2 * i] = acc2[i].x; acc[2 * i + 1] = acc2[i].y; }
#pragma unroll
  for (int i = 0; i < 8; ++i) {
    acc[i] += __shfl_xor(acc[i], 4);
    acc[i] += __shfl_xor(acc[i], 8);
    acc[i] += __shfl_xor(acc[i], 16);
    acc[i] += __shfl_xor(acc[i], 32);
  }
  d += __shfl_xor(d, 4); d += __shfl_xor(d, 8);
  d += __shfl_xor(d, 16); d += __shfl_xor(d, 32);
  if (g16 == 0) {
    float inv = 1.f / (d + 1e-16f);
    float4 b0 = *(const float4*)&bias[q * 8];
    float4 b1 = *(const float4*)&bias[q * 8 + 4];
    float4 o0, o1;
    o0.x = fmaxf(fmaf(acc[0], inv, b0.x), 0.f);
    o0.y = fmaxf(fmaf(acc[1], inv, b0.y), 0.f);
    o0.z = fmaxf(fmaf(acc[2], inv, b0.z), 0.f);
    o0.w = fmaxf(fmaf(acc[3], inv, b0.w), 0.f);
    o1.x = fmaxf(fmaf(acc[4], inv, b1.x), 0.f);
    o1.y = fmaxf(fmaf(acc[5], inv, b1.y), 0.f);
    o1.z = fmaxf(fmaf(acc[6], inv, b1.z), 0.f);
    o1.w = fmaxf(fmaf(acc[7], inv, b1.w), 0.f);
    *(float4*)&hout[(size_t)wid * 32 + q * 8]     = o0;
    *(float4*)&hout[(size_t)wid * 32 + q * 8 + 4] = o1;
  }
}

// ---------------- pooling: 256-block partial + 64-block head ----------------
__global__ __launch_bounds__(256) void pool_partial_kernel(const float* __restrict__ h2,
    const float* __restrict__ gate, const int* __restrict__ batch,
    float* __restrict__ partial, int n)
{
  int sb = blockIdx.x;
  int g = sb >> 2, part = sb & 3;
  int t = threadIdx.x;
  int lo = 0, hi = n;
  while (lo < hi) { int mid = (lo + hi) >> 1; if (batch[mid] < g) lo = mid + 1; else hi = mid; }
  int s = lo;
  lo = s; hi = n;
  while (lo < hi) { int mid = (lo + hi) >> 1; if (batch[mid] < g + 1) lo = mid + 1; else hi = mid; }
  int e = lo;
  int len = e - s;
  int q0 = s + (len * part) / 4;
  int q1 = s + (len * (part + 1)) / 4;

  int c = t & 31, grp = t >> 5;
  float acc = 0.f, dsum = 0.f;
  for (int i = q0 + grp; i < q1; i += 8) {
    float sv = __expf(gate[i]);
    acc += sv * h2[(size_t)i * 32 + c];
    if (c == 0) dsum += sv;
  }
  __shared__ float accs[8][33];
  __shared__ float dss[8];
  accs[grp][c] = acc;
  if (c == 0) dss[grp] = dsum;
  __syncthreads();
  if (t < 32) {
    float a = 0.f, dd = 0.f;
#pragma unroll
    for (int k = 0; k < 8; ++k) { a += accs[k][t]; dd += dss[k]; }
    partial[sb * 33 + t] = a;
    if (t == 0) partial[sb * 33 + 32] = dd;
  }
}

__global__ __launch_bounds__(64) void pool_final_kernel(const float* __restrict__ partial,
    const float* __restrict__ W1, const float* __restrict__ b1,
    const float* __restrict__ W2, const float* __restrict__ b2,
    float* __restrict__ out)
{
  int g = blockIdx.x;
  int t = threadIdx.x;
  if (t >= 32) return;
  float a = 0.f, dd = 0.f;
#pragma unroll
  for (int p = 0; p < 4; ++p) {
    int sb = g * 4 + p;
    a  += partial[sb * 33 + t];
    dd += partial[sb * 33 + 32];
  }
  float pv = a / (dd + 1e-16f);
  float qv = 0.f;
  for (int cc = 0; cc < 32; ++cc)
    qv = fmaf(__shfl(pv, cc, 32), W1[cc * 32 + t], qv);
  qv = fmaxf(qv + b1[t], 0.f);
  float r = qv * W2[t];
  r += __shfl_xor(r, 1, 32);  r += __shfl_xor(r, 2, 32);
  r += __shfl_xor(r, 4, 32);  r += __shfl_xor(r, 8, 32);
  r += __shfl_xor(r, 16, 32);
  if (t == 0) out[g] = r + b2[0];
}

// ---------------- host ----------------
extern "C" void kernel_launch(void* const* d_in, const int* in_sizes, int n_in,
                              void* d_out, int out_size, void* d_ws, size_t ws_size,
                              hipStream_t stream)
{
  const float* x     = (const float*)d_in[0];
  const int*   ei    = (const int*)d_in[1];
  const int*   batch = (const int*)d_in[2];
  const float* Wl1   = (const float*)d_in[3];
  const float* bl1   = (const float*)d_in[4];
  const float* Wr1   = (const float*)d_in[5];
  const float* br1   = (const float*)d_in[6];
  const float* att1  = (const float*)d_in[7];
  const float* bias1 = (const float*)d_in[8];
  const float* Wl2   = (const float*)d_in[9];
  const float* bl2   = (const float*)d_in[10];
  const float* Wr2   = (const float*)d_in[11];
  const float* br2   = (const float*)d_in[12];
  const float* att2  = (const float*)d_in[13];
  const float* bias2 = (const float*)d_in[14];
  const float* Wg1   = (const float*)d_in[15];
  const float* bg1   = (const float*)d_in[16];
  const float* Wg2   = (const float*)d_in[17];
  const float* bg2   = (const float*)d_in[18];
  const float* W1    = (const float*)d_in[19];
  const float* b1    = (const float*)d_in[20];
  const float* W2    = (const float*)d_in[21];
  const float* b2    = (const float*)d_in[22];
  float* out = (float*)d_out;

  const int n = in_sizes[2];
  const int E = in_sizes[1] / 2;
  const int Etot = E + n;
  const int nbuk = (n + 255) / 256;   // 391 for n=100k (<=511 required)

  float* fws = (float*)d_ws;
  size_t nf64 = (size_t)n * 64;
  float* bufA = fws;                      // xl1(bf16) -> xl2(bf16)|xr2(f32)
  float* bufB = bufA + nf64;              // xr1 -> h2 | gate
  float* bufC = bufB + nf64;              // partition scratch during build, then h
  unsigned short* xl1 = (unsigned short*)bufA;      // n*64 bf16
  float* xr1 = bufB;                                 // n*64 f32
  float* hbuf = bufC;                                // n*64 f32
  unsigned short* xl2 = (unsigned short*)bufA;       // n*32 bf16
  float* xr2 = bufA + (size_t)n * 16;                // n*32 f32 (after n*32 bf16)
  float* h2  = bufB;                                 // n*32 f32
  float* gate = bufB + (size_t)n * 32;               // n f32
  unsigned* scratch = (unsigned*)bufC;    // E u32, dead before gat1 writes hbuf
  int* ip       = (int*)(bufC + nf64);
  int* row_ptr  = ip;  ip += (n + 2);
  int* buk_cnt  = ip;  ip += 512;
  int* sbuk_off = ip;  ip += 520;
  int* buk_run  = ip;  ip += 512;
  int* csr_src  = ip;  ip += Etot;        // E + n ints
  unsigned short* WT1 = (unsigned short*)ip;         // 128*128 bf16
  unsigned short* WT2 = WT1 + 128 * 128;             // 64*64 bf16
  float* ppart = (float*)(WT2 + 64 * 64);            // 256*33 f32 pool partials

  hipMemsetAsync(buk_cnt, 0, 512 * sizeof(int), stream);

  int mb64 = (n + 63) / 64;   // 64-row GEMM tiles

  wtrans_kernel<<<11, 256, 0, stream>>>(Wl1, Wr1, WT1, Wl2, Wr2, WT2);

  mm_mfma_kernel<128, 64, 8><<<mb64, 512, 0, stream>>>(x, WT1, bl1, br1, xl1, xr1, n);

  bucket_hist_kernel<<<256, 256, 0, stream>>>(ei, buk_cnt, E, nbuk);
  scan_buckets_kernel<<<1, 512, 0, stream>>>(buk_cnt, sbuk_off, buk_run, nbuk, E);
  partition_kernel<<<256, 256, 0, stream>>>(ei, buk_run, scratch, E, nbuk);
  bucket_fill_kernel<<<nbuk, 256, 0, stream>>>(scratch, sbuk_off, row_ptr, csr_src, n, nbuk);

  int gatblocks = (n + 3) / 4;   // 4 waves (dsts) per block
  gat1_kernel<<<gatblocks, 256, 0, stream>>>(xl1, xr1, row_ptr, csr_src, att1, bias1, hbuf, n);

  mm_mfma_kernel<64, 32, 4><<<mb64, 256, 0, stream>>>(hbuf, WT2, bl2, br2, xl2, xr2, n);

  gat2_kernel<<<gatblocks, 256, 0, stream>>>(xl2, xr2, row_ptr, csr_src, att2, bias2, h2, n);

  gate_kernel<<<(n + 255) / 256, 256, 0, stream>>>(h2, Wg1, bg1, Wg2, bg2, gate, n);

  pool_partial_kernel<<<256, 256, 0, stream>>>(h2, gate, batch, ppart, n);
  pool_final_kernel<<<64, 64, 0, stream>>>(ppart, W1, b1, W2, b2, out);
}

// Round 16
// 210.741 us; speedup vs baseline: 1.0126x; 1.0126x over previous
//
#include <hip/hip_runtime.h>
#include <math.h>

// GATv2Regressor: N=100k nodes, E=1.6M edges (+N self-loops), F=128, C=32, H1=2, G=64.
// CSR-by-dst GAT layers (no-max softmax via exp2 with log2e folded into att coeffs,
// 8ch/lane, 2-DPP quad reductions, |t|-folded leaky, load-ahead gathers, bf16 tables);
// CSR via bucket partition (int4 edge loads); dense via B-resident bf16 MFMA GEMMs;
// pooling split into 256-block partial + 64-block head for full-chip utilization.

constexpr float LOG2E = 1.44269504088896f;

typedef short bf16x8 __attribute__((ext_vector_type(8)));   // 8 bf16 (4 VGPRs)
typedef float f32x4  __attribute__((ext_vector_type(4)));   // MFMA accumulator

// DPP quad_perm: xor1 = 0xB1, xor2 = 0x4E.  REDUCE4 = sum within aligned 4-lane quads.
#define DPP_ADD(v, ctrl)                                                             \
  do {                                                                               \
    int _t = __builtin_amdgcn_update_dpp(0, __float_as_int(v), (ctrl), 0xF, 0xF, true); \
    (v) = (v) + __int_as_float(_t);                                                  \
  } while (0)
#define REDUCE4(v) do { DPP_ADD(v, 0xB1); DPP_ADD(v, 0x4E); } while (0)

__device__ __forceinline__ unsigned short f2bf(float f) {   // RNE f32 -> bf16
  unsigned u = __float_as_uint(f);
  return (unsigned short)((u + 0x7FFFu + ((u >> 16) & 1u)) >> 16);
}
__device__ __forceinline__ float bfLO(unsigned u) { return __uint_as_float(u << 16); }
__device__ __forceinline__ float bfHI(unsigned u) { return __uint_as_float(u & 0xFFFF0000u); }

// ---------------- W transpose (both layers in one launch) ----------------
// WT[col][k] bf16; cols 0..NHALF-1 = Wl, NHALF..2*NHALF-1 = Wr.
__global__ __launch_bounds__(256) void wtrans_kernel(
    const float* __restrict__ Wl1, const float* __restrict__ Wr1, unsigned short* __restrict__ WT1,
    const float* __restrict__ Wl2, const float* __restrict__ Wr2, unsigned short* __restrict__ WT2)
{
  int g = blockIdx.x * 256 + threadIdx.x;
  int g1 = 128 * 16;            // 2*64 cols * (128/8) kb-groups for layer 1
  int K, NHALF, col, kb;
  const float *Wl, *Wr; unsigned short* WT;
  if (g < g1) { K = 128; NHALF = 64; Wl = Wl1; Wr = Wr1; WT = WT1; }
  else        { g -= g1; if (g >= 64 * 8) return; K = 64; NHALF = 32; Wl = Wl2; Wr = Wr2; WT = WT2; }
  col = g / (K / 8);
  kb  = (g % (K / 8)) * 8;
  const float* W = (col < NHALF) ? Wl : Wr;
  int c = (col < NHALF) ? col : col - NHALF;
  float v[8];
#pragma unroll
  for (int i = 0; i < 8; ++i) v[i] = W[(size_t)(kb + i) * NHALF + c];
  ushort4 h0, h1;
  h0.x = f2bf(v[0]); h0.y = f2bf(v[1]); h0.z = f2bf(v[2]); h0.w = f2bf(v[3]);
  h1.x = f2bf(v[4]); h1.y = f2bf(v[5]); h1.z = f2bf(v[6]); h1.w = f2bf(v[7]);
  *(ushort4*)&WT[(size_t)col * K + kb]     = h0;
  *(ushort4*)&WT[(size_t)col * K + kb + 4] = h1;
}

// ---------------- dense: bf16 MFMA dual-weight GEMM, B-resident ----------------
template<int K, int NHALF, int WAVES>
__global__ __launch_bounds__(WAVES * 64) void mm_mfma_kernel(const float* __restrict__ x,
    const unsigned short* __restrict__ WT,
    const float* __restrict__ bl, const float* __restrict__ br,
    unsigned short* __restrict__ outl, float* __restrict__ outr, int n)
{
  constexpr int KC = K / 32;        // k chunks (B frags per wave)
  constexpr int NT_THREADS = WAVES * 64;
  __shared__ unsigned short xs[64 * K];
  const int t = threadIdx.x;
  const int rowbase = blockIdx.x * 64;
  const int w = t >> 6, l = t & 63;
  const int bcol = w * 16 + (l & 15);
  const int kgrp = (l >> 4) * 8;

  bf16x8 bfr[KC];
#pragma unroll
  for (int kc = 0; kc < KC; ++kc)
    bfr[kc] = *(const bf16x8*)&WT[(size_t)bcol * K + kc * 32 + kgrp];

  constexpr int GPT = (64 * K / 8) / NT_THREADS;
#pragma unroll
  for (int g = 0; g < GPT; ++g) {
    int idx = t + g * NT_THREADS;
    int row = idx / (K / 8);
    int kb  = (idx % (K / 8)) * 8;
    int grow = rowbase + row;
    float4 a0 = make_float4(0.f, 0.f, 0.f, 0.f), a1 = a0;
    if (grow < n) {
      a0 = *(const float4*)&x[(size_t)grow * K + kb];
      a1 = *(const float4*)&x[(size_t)grow * K + kb + 4];
    }
    ushort4 h0, h1;
    h0.x = f2bf(a0.x); h0.y = f2bf(a0.y); h0.z = f2bf(a0.z); h0.w = f2bf(a0.w);
    h1.x = f2bf(a1.x); h1.y = f2bf(a1.y); h1.z = f2bf(a1.z); h1.w = f2bf(a1.w);
    int ksw = kb ^ ((row & 7) << 3);
    *(ushort4*)&xs[row * K + ksw]     = h0;
    *(ushort4*)&xs[row * K + ksw + 4] = h1;
  }
  __syncthreads();

  f32x4 zero = {0.f, 0.f, 0.f, 0.f};
  f32x4 acc[4];
#pragma unroll
  for (int i = 0; i < 4; ++i) acc[i] = zero;

#pragma unroll
  for (int rt = 0; rt < 4; ++rt) {
    int arow = rt * 16 + (l & 15);
    int asw  = (arow & 7) << 3;
#pragma unroll
    for (int kc = 0; kc < KC; ++kc) {
      bf16x8 a = *(const bf16x8*)&xs[arow * K + ((kc * 32 + kgrp) ^ asw)];
      acc[rt] = __builtin_amdgcn_mfma_f32_16x16x32_bf16(a, bfr[kc], acc[rt], 0, 0, 0);
    }
  }

  const bool isl = bcol < NHALF;
  const int col = isl ? bcol : bcol - NHALF;
  const float bb = isl ? bl[col] : br[col];
#pragma unroll
  for (int rt = 0; rt < 4; ++rt) {
    int r0 = rowbase + rt * 16 + (l >> 4) * 4;
#pragma unroll
    for (int j = 0; j < 4; ++j) {
      int row = r0 + j;
      if (row < n) {
        float v = acc[rt][j] + bb;
        if (isl) outl[(size_t)row * NHALF + col] = f2bf(v);
        else     outr[(size_t)row * NHALF + col] = v;
      }
    }
  }
}

// gate[n] = relu(h2 @ Wg1 + bg1) @ Wg2 + bg2 (fused, thread-per-row)
__global__ __launch_bounds__(256) void gate_kernel(const float* __restrict__ h2,
    const float* __restrict__ Wg1, const float* __restrict__ bg1,
    const float* __restrict__ Wg2, const float* __restrict__ bg2,
    float* __restrict__ gate, int n)
{
  int row = blockIdx.x * 256 + threadIdx.x;
  int rr = (row < n) ? row : 0;
  const float* hp = h2 + (size_t)rr * 32;
  float acc[32];
#pragma unroll
  for (int c = 0; c < 32; ++c) acc[c] = 0.f;
  for (int k0 = 0; k0 < 32; k0 += 8) {
    float4 a0 = *(const float4*)(hp + k0 + 0);
    float4 a1 = *(const float4*)(hp + k0 + 4);
    float xk[8];
    xk[0]=a0.x; xk[1]=a0.y; xk[2]=a0.z; xk[3]=a0.w;
    xk[4]=a1.x; xk[5]=a1.y; xk[6]=a1.z; xk[7]=a1.w;
#pragma unroll
    for (int kk = 0; kk < 8; ++kk) {
      const float* wv = Wg1 + (size_t)(k0 + kk) * 32;
#pragma unroll
      for (int c = 0; c < 32; ++c) acc[c] = fmaf(xk[kk], wv[c], acc[c]);
    }
  }
  if (row < n) {
    float g = 0.f;
#pragma unroll
    for (int c = 0; c < 32; ++c)
      g = fmaf(fmaxf(acc[c] + bg1[c], 0.f), Wg2[c], g);
    gate[row] = g + bg2[0];
  }
}

// ---------------- CSR build via bucket partition (256 dsts/bucket) ----------------
__global__ __launch_bounds__(256) void bucket_hist_kernel(const int* __restrict__ ei,
    int* __restrict__ buk_cnt, int E, int nbuk)
{
  __shared__ int h[512];
  for (int b = threadIdx.x; b < 512; b += 256) h[b] = 0;
  __syncthreads();
  int total = gridDim.x * 1024;
  for (int i = (blockIdx.x * 256 + threadIdx.x) * 4; i < E; i += total) {
    if (i + 3 < E) {
      int4 d = *(const int4*)&ei[E + i];
      atomicAdd(&h[((unsigned)d.x) >> 8], 1);
      atomicAdd(&h[((unsigned)d.y) >> 8], 1);
      atomicAdd(&h[((unsigned)d.z) >> 8], 1);
      atomicAdd(&h[((unsigned)d.w) >> 8], 1);
    } else {
      for (int j = i; j < E; ++j) atomicAdd(&h[((unsigned)ei[E + j]) >> 8], 1);
    }
  }
  __syncthreads();
  for (int b = threadIdx.x; b < nbuk; b += 256)
    if (h[b]) atomicAdd(&buk_cnt[b], h[b]);
}

__global__ __launch_bounds__(512) void scan_buckets_kernel(const int* __restrict__ buk_cnt,
    int* __restrict__ sbuk_off, int* __restrict__ buk_run, int nbuk, int E)
{
  __shared__ int lds[512];
  int t = threadIdx.x;
  int v = (t < nbuk) ? buk_cnt[t] : 0;
  lds[t] = v; __syncthreads();
  for (int off = 1; off < 512; off <<= 1) {
    int x = (t >= off) ? lds[t - off] : 0;
    __syncthreads();
    lds[t] += x;
    __syncthreads();
  }
  int excl = lds[t] - v;
  if (t < nbuk) { sbuk_off[t] = excl; buk_run[t] = excl; }
  if (t == nbuk) sbuk_off[t] = E;
}

// packed u32: src (17 bits) | dstlo (8 bits) << 17
__global__ __launch_bounds__(256) void partition_kernel(const int* __restrict__ ei,
    int* __restrict__ buk_run, unsigned* __restrict__ scratch, int E, int nbuk)
{
  __shared__ int lcnt[512];
  __shared__ int lbase[512];
  int t = threadIdx.x;
  for (int b = t; b < 512; b += 256) lcnt[b] = 0;
  __syncthreads();
  int chunk = ((E + gridDim.x - 1) / gridDim.x + 3) & ~3;
  int s = blockIdx.x * chunk, e = min(E, s + chunk);
  for (int i = s + t * 4; i < e; i += 1024) {
    if (i + 3 < e) {
      int4 d = *(const int4*)&ei[E + i];
      atomicAdd(&lcnt[((unsigned)d.x) >> 8], 1);
      atomicAdd(&lcnt[((unsigned)d.y) >> 8], 1);
      atomicAdd(&lcnt[((unsigned)d.z) >> 8], 1);
      atomicAdd(&lcnt[((unsigned)d.w) >> 8], 1);
    } else {
      for (int j = i; j < e; ++j) atomicAdd(&lcnt[((unsigned)ei[E + j]) >> 8], 1);
    }
  }
  __syncthreads();
  for (int b = t; b < nbuk; b += 256) {
    int c = lcnt[b];
    lbase[b] = c ? atomicAdd(&buk_run[b], c) : 0;
    lcnt[b] = 0;
  }
  __syncthreads();
  for (int i = s + t * 4; i < e; i += 1024) {
    if (i + 3 < e) {
      int4 sv = *(const int4*)&ei[i];
      int4 dv = *(const int4*)&ei[E + i];
#define SCAT(SS, DD) { int b = ((unsigned)(DD)) >> 8;                        \
      int r = atomicAdd(&lcnt[b], 1);                                        \
      scratch[lbase[b] + r] = (unsigned)(SS) | ((((unsigned)(DD)) & 255u) << 17); }
      SCAT(sv.x, dv.x) SCAT(sv.y, dv.y) SCAT(sv.z, dv.z) SCAT(sv.w, dv.w)
    } else {
      for (int j = i; j < e; ++j) {
        int ss = ei[j]; unsigned dd = (unsigned)ei[E + j];
        SCAT(ss, dd)
      }
#undef SCAT
    }
  }
}

__global__ __launch_bounds__(256) void bucket_fill_kernel(const unsigned* __restrict__ scratch,
    const int* __restrict__ sbuk_off, int* __restrict__ row_ptr,
    int* __restrict__ csr_src, int n, int nbuk)
{
  __shared__ int lcnt[256], sexcl[256], cnt2[256];
  int b = blockIdx.x, t = threadIdx.x;
  int dst0 = b << 8;
  int ndst = min(256, n - dst0);
  int s = sbuk_off[b], e = sbuk_off[b + 1];
  int base = s + dst0;
  lcnt[t] = (t < ndst) ? 1 : 0;   // +1 self-loop per dst
  __syncthreads();
  for (int i = s + t; i < e; i += 256)
    atomicAdd(&lcnt[scratch[i] >> 17], 1);
  __syncthreads();
  int c0 = lcnt[t];
  for (int off = 1; off < 256; off <<= 1) {
    int x = (t >= off) ? lcnt[t - off] : 0;
    __syncthreads();
    lcnt[t] += x;
    __syncthreads();
  }
  int ex = lcnt[t] - c0;
  sexcl[t] = ex;
  cnt2[t] = 1;
  if (t < ndst) {
    row_ptr[dst0 + t] = base + ex;
    csr_src[base + ex] = dst0 + t;        // self-loop in slot 0
  }
  if (b == nbuk - 1 && t == 0) row_ptr[n] = sbuk_off[nbuk] + n;
  __syncthreads();
  for (int i = s + t; i < e; i += 256) {
    unsigned u = scratch[i];
    int dl = u >> 17;
    int src = u & 0x1FFFF;
    int pos = base + sexcl[dl] + atomicAdd(&cnt2[dl], 1);
    csr_src[pos] = src;
  }
}

// ---------------- GATv2 layer 1: heads=2, ch=32; one wave/dst, 8 edges/iter ----------------
// 8 lanes/edge (g8 = l>>3); lane q = l&7 owns channels q*8..q*8+7.
// leaky(t)*att*log2e folded: p = exp2(v). |t| via free VOP3 abs modifier.
__global__ __launch_bounds__(256) void gat1_kernel(const unsigned short* __restrict__ xl,
    const float* __restrict__ xr, const int* __restrict__ row_ptr,
    const int* __restrict__ csr_src, const float* __restrict__ att,
    const float* __restrict__ bias, float* __restrict__ hout, int n)
{
  int wid = (blockIdx.x * 256 + threadIdx.x) >> 6;
  if (wid >= n) return;
  wid = __builtin_amdgcn_readfirstlane(wid);
  int l = threadIdx.x & 63;
  int g8 = l >> 3;
  int q = l & 7;
  float xrv[8], a6[8], a4[8];
  {
    float4 x0 = *(const float4*)&xr[(size_t)wid * 64 + q * 8];
    float4 x1 = *(const float4*)&xr[(size_t)wid * 64 + q * 8 + 4];
    float4 c0 = *(const float4*)&att[q * 8];
    float4 c1 = *(const float4*)&att[q * 8 + 4];
    xrv[0]=x0.x; xrv[1]=x0.y; xrv[2]=x0.z; xrv[3]=x0.w;
    xrv[4]=x1.x; xrv[5]=x1.y; xrv[6]=x1.z; xrv[7]=x1.w;
    float av[8];
    av[0]=c0.x; av[1]=c0.y; av[2]=c0.z; av[3]=c0.w;
    av[4]=c1.x; av[5]=c1.y; av[6]=c1.z; av[7]=c1.w;
#pragma unroll
    for (int i = 0; i < 8; ++i) {
      a6[i] = 0.6f * LOG2E * av[i];
      a4[i] = 0.4f * LOG2E * av[i];
    }
  }
  int s = row_ptr[wid], e = row_ptr[wid + 1];
  float acc[8];
#pragma unroll
  for (int i = 0; i < 8; ++i) acc[i] = 0.f;
  float d = 0.f;

#define LOAD1(CB, hv) {                                                       \
    int src_ = csr_src[min((CB) + g8, e - 1)];                                \
    hv = *(const int4*)&xl[(size_t)src_ * 64 + q * 8]; }

  int4 cur;
  LOAD1(s, cur)
  for (int cb = s; cb < e; cb += 8) {
    int4 nxt;
    LOAD1(min(cb + 8, e - 1), nxt)       // load-ahead (clamped, safe)
    float xc[8];
    xc[0] = bfLO((unsigned)cur.x); xc[1] = bfHI((unsigned)cur.x);
    xc[2] = bfLO((unsigned)cur.y); xc[3] = bfHI((unsigned)cur.y);
    xc[4] = bfLO((unsigned)cur.z); xc[5] = bfHI((unsigned)cur.z);
    xc[6] = bfLO((unsigned)cur.w); xc[7] = bfHI((unsigned)cur.w);
    float v = 0.f;
#pragma unroll
    for (int i = 0; i < 8; ++i) {
      float t = xc[i] + xrv[i];
      v = fmaf(t, a6[i], v);
      v = fmaf(fabsf(t), a4[i], v);      // abs = free VOP3 modifier
    }
    REDUCE4(v);                           // per-head logit (4-lane quads)
    float p = __builtin_amdgcn_exp2f(v);  // exp(logit) via folded log2e
    p = (cb + g8 < e) ? p : 0.f;
    d += p;
#pragma unroll
    for (int i = 0; i < 8; ++i) acc[i] = fmaf(p, xc[i], acc[i]);
    cur = nxt;
  }
#undef LOAD1
#pragma unroll
  for (int i = 0; i < 8; ++i) {
    acc[i] += __shfl_xor(acc[i], 8);
    acc[i] += __shfl_xor(acc[i], 16);
    acc[i] += __shfl_xor(acc[i], 32);
  }
  d += __shfl_xor(d, 8); d += __shfl_xor(d, 16); d += __shfl_xor(d, 32);
  if (g8 == 0) {
    float inv = 1.f / (d + 1e-16f);
    float4 b0 = *(const float4*)&bias[q * 8];
    float4 b1 = *(const float4*)&bias[q * 8 + 4];
    float4 o0, o1;
    o0.x = fmaxf(fmaf(acc[0], inv, b0.x), 0.f);
    o0.y = fmaxf(fmaf(acc[1], inv, b0.y), 0.f);
    o0.z = fmaxf(fmaf(acc[2], inv, b0.z), 0.f);
    o0.w = fmaxf(fmaf(acc[3], inv, b0.w), 0.f);
    o1.x = fmaxf(fmaf(acc[4], inv, b1.x), 0.f);
    o1.y = fmaxf(fmaf(acc[5], inv, b1.y), 0.f);
    o1.z = fmaxf(fmaf(acc[6], inv, b1.z), 0.f);
    o1.w = fmaxf(fmaf(acc[7], inv, b1.w), 0.f);
    *(float4*)&hout[(size_t)wid * 64 + q * 8]     = o0;
    *(float4*)&hout[(size_t)wid * 64 + q * 8 + 4] = o1;
  }
}

// ---------------- GATv2 layer 2: heads=1, ch=32; one wave/dst, 16 edges/iter ----------------
__global__ __launch_bounds__(256) void gat2_kernel(const unsigned short* __restrict__ xl,
    const float* __restrict__ xr, const int* __restrict__ row_ptr,
    const int* __restrict__ csr_src, const float* __restrict__ att,
    const float* __restrict__ bias, float* __restrict__ hout, int n)
{
  int wid = (blockIdx.x * 256 + threadIdx.x) >> 6;
  if (wid >= n) return;
  wid = __builtin_amdgcn_readfirstlane(wid);
  int l = threadIdx.x & 63;
  int g16 = l >> 2;
  int q = l & 3;
  float xrv[8], a6[8], a4[8];
  {
    float4 x0 = *(const float4*)&xr[(size_t)wid * 32 + q * 8];
    float4 x1 = *(const float4*)&xr[(size_t)wid * 32 + q * 8 + 4];
    float4 c0 = *(const float4*)&att[q * 8];
    float4 c1 = *(const float4*)&att[q * 8 + 4];
    xrv[0]=x0.x; xrv[1]=x0.y; xrv[2]=x0.z; xrv[3]=x0.w;
    xrv[4]=x1.x; xrv[5]=x1.y; xrv[6]=x1.z; xrv[7]=x1.w;
    float av[8];
    av[0]=c0.x; av[1]=c0.y; av[2]=c0.z; av[3]=c0.w;
    av[4]=c1.x; av[5]=c1.y; av[6]=c1.z; av[7]=c1.w;
#pragma unroll
    for (int i = 0; i < 8; ++i) {
      a6[i] = 0.6f * LOG2E * av[i];
      a4[i] = 0.4f * LOG2E * av[i];
    }
  }
  int s = row_ptr[wid], e = row_ptr[wid + 1];
  int deg = e - s;
  float acc[8];
#pragma unroll
  for (int i = 0; i < 8; ++i) acc[i] = 0.f;
  float d = 0.f;

#define LOAD2(I0, hv) {                                                       \
    int src_ = csr_src[s + min((I0) + g16, deg - 1)];                         \
    hv = *(const int4*)&xl[(size_t)src_ * 32 + q * 8]; }

  int4 cur;
  LOAD2(0, cur)
  for (int i0 = 0; i0 < deg; i0 += 16) {
    int4 nxt;
    LOAD2(min(i0 + 16, deg - 1), nxt)
    float xc[8];
    xc[0] = bfLO((unsigned)cur.x); xc[1] = bfHI((unsigned)cur.x);
    xc[2] = bfLO((unsigned)cur.y); xc[3] = bfHI((unsigned)cur.y);
    xc[4] = bfLO((unsigned)cur.z); xc[5] = bfHI((unsigned)cur.z);
    xc[6] = bfLO((unsigned)cur.w); xc[7] = bfHI((unsigned)cur.w);
    float v = 0.f;
#pragma unroll
    for (int i = 0; i < 8; ++i) {
      float t = xc[i] + xrv[i];
      v = fmaf(t, a6[i], v);
      v = fmaf(fabsf(t), a4[i], v);
    }
    REDUCE4(v);                           // full logit (4 lanes per edge)
    float p = __builtin_amdgcn_exp2f(v);
    p = (i0 + g16 < deg) ? p : 0.f;
    d += p;
#pragma unroll
    for (int i = 0; i < 8; ++i) acc[i] = fmaf(p, xc[i], acc[i]);
    cur = nxt;
  }
#undef LOAD2
#pragma unroll
  for (int i = 0; i < 8; ++i) {
    acc[i] += __shfl_xor(acc[i], 4);
    acc[i] += __shfl_xor(acc[i], 8);
    acc[i] += __shfl_xor(acc[i], 16);
    acc[i] += __shfl_xor(acc[i], 32);
  }
  d += __shfl_xor(d, 4); d += __shfl_xor(d, 8);
  d += __shfl_xor(d, 16); d += __shfl_xor(d, 32);
  if (g16 == 0) {
    float inv = 1.f / (d + 1e-16f);
    float4 b0 = *(const float4*)&bias[q * 8];
    float4 b1 = *(const float4*)&bias[q * 8 + 4];
    float4 o0, o1;
    o0.x = fmaxf(fmaf(acc[0], inv, b0.x), 0.f);
    o0.y = fmaxf(fmaf(acc[1], inv, b0.y), 0.f);
    o0.z = fmaxf(fmaf(acc[2], inv, b0.z), 0.f);
    o0.w = fmaxf(fmaf(acc[3], inv, b0.w), 0.f);
    o1.x = fmaxf(fmaf(acc[4], inv, b1.x), 0.f);
    o1.y = fmaxf(fmaf(acc[5], inv, b1.y), 0.f);
    o1.z = fmaxf(fmaf(acc[6], inv, b1.z), 0.f);
    o1.w = fmaxf(fmaf(acc[7], inv, b1.w), 0.f);
    *(float4*)&hout[(size_t)wid * 32 + q * 8]     = o0;
    *(float4*)&hout[(size_t)wid * 32 + q * 8 + 4] = o1;
  }
}

// ---------------- pooling: 256-block partial (4 sub-blocks per graph, no-max exp) ----------------
__global__ __launch_bounds__(256) void pool_partial_kernel(const float* __restrict__ h2,
    const float* __restrict__ gate, const int* __restrict__ batch,
    float* __restrict__ partial, int n)
{
  int sb = blockIdx.x;
  int g = sb >> 2, part = sb & 3;
  int t = threadIdx.x;
  int lo = 0, hi = n;
  while (lo < hi) { int mid = (lo + hi) >> 1; if (batch[mid] < g) lo = mid + 1; else hi = mid; }
  int s = lo;
  lo = s; hi = n;
  while (lo < hi) { int mid = (lo + hi) >> 1; if (batch[mid] < g + 1) lo = mid + 1; else hi = mid; }
  int e = lo;
  int len = e - s;
  int q0 = s + (len * part) / 4;
  int q1 = s + (len * (part + 1)) / 4;

  int c = t & 31, grp = t >> 5;   // 8 node-groups x 32 channels
  float acc = 0.f, dsum = 0.f;
  for (int i = q0 + grp; i < q1; i += 8) {
    float sv = __expf(gate[i]);   // no max subtraction: gate logits are O(1), exp safe
    acc += sv * h2[(size_t)i * 32 + c];
    if (c == 0) dsum += sv;
  }
  __shared__ float accs[8][33];
  __shared__ float dss[8];
  accs[grp][c] = acc;
  if (c == 0) dss[grp] = dsum;
  __syncthreads();
  if (t < 32) {
    float a = 0.f, dd = 0.f;
#pragma unroll
    for (int k = 0; k < 8; ++k) { a += accs[k][t]; dd += dss[k]; }
    partial[sb * 33 + t] = a;
    if (t == 0) partial[sb * 33 + 32] = dd;
  }
}

// final: sum 4 partials per graph + head MLP
__global__ __launch_bounds__(64) void pool_final_kernel(const float* __restrict__ partial,
    const float* __restrict__ W1, const float* __restrict__ b1,
    const float* __restrict__ W2, const float* __restrict__ b2,
    float* __restrict__ out)
{
  int g = blockIdx.x;
  int t = threadIdx.x;
  if (t >= 32) return;
  float a = 0.f, dd = 0.f;
#pragma unroll
  for (int p = 0; p < 4; ++p) {
    int sb = g * 4 + p;
    a  += partial[sb * 33 + t];
    dd += partial[sb * 33 + 32];
  }
  float pv = a / (dd + 1e-16f);
  float qv = 0.f;
  for (int cc = 0; cc < 32; ++cc)
    qv = fmaf(__shfl(pv, cc, 32), W1[cc * 32 + t], qv);
  qv = fmaxf(qv + b1[t], 0.f);
  float r = qv * W2[t];
  r += __shfl_xor(r, 1, 32);  r += __shfl_xor(r, 2, 32);
  r += __shfl_xor(r, 4, 32);  r += __shfl_xor(r, 8, 32);
  r += __shfl_xor(r, 16, 32);
  if (t == 0) out[g] = r + b2[0];
}

// ---------------- host ----------------
extern "C" void kernel_launch(void* const* d_in, const int* in_sizes, int n_in,
                              void* d_out, int out_size, void* d_ws, size_t ws_size,
                              hipStream_t stream)
{
  const float* x     = (const float*)d_in[0];
  const int*   ei    = (const int*)d_in[1];
  const int*   batch = (const int*)d_in[2];
  const float* Wl1   = (const float*)d_in[3];
  const float* bl1   = (const float*)d_in[4];
  const float* Wr1   = (const float*)d_in[5];
  const float* br1   = (const float*)d_in[6];
  const float* att1  = (const float*)d_in[7];
  const float* bias1 = (const float*)d_in[8];
  const float* Wl2   = (const float*)d_in[9];
  const float* bl2   = (const float*)d_in[10];
  const float* Wr2   = (const float*)d_in[11];
  const float* br2   = (const float*)d_in[12];
  const float* att2  = (const float*)d_in[13];
  const float* bias2 = (const float*)d_in[14];
  const float* Wg1   = (const float*)d_in[15];
  const float* bg1   = (const float*)d_in[16];
  const float* Wg2   = (const float*)d_in[17];
  const float* bg2   = (const float*)d_in[18];
  const float* W1    = (const float*)d_in[19];
  const float* b1    = (const float*)d_in[20];
  const float* W2    = (const float*)d_in[21];
  const float* b2    = (const float*)d_in[22];
  float* out = (float*)d_out;

  const int n = in_sizes[2];
  const int E = in_sizes[1] / 2;
  const int Etot = E + n;
  const int nbuk = (n + 255) / 256;   // 391 for n=100k (<=511 required)

  float* fws = (float*)d_ws;
  size_t nf64 = (size_t)n * 64;
  float* bufA = fws;                      // xl1(bf16) -> xl2(bf16)|xr2(f32)
  float* bufB = bufA + nf64;              // xr1 -> h2 | gate
  float* bufC = bufB + nf64;              // partition scratch during build, then h
  unsigned short* xl1 = (unsigned short*)bufA;      // n*64 bf16
  float* xr1 = bufB;                                 // n*64 f32
  float* hbuf = bufC;                                // n*64 f32
  unsigned short* xl2 = (unsigned short*)bufA;       // n*32 bf16
  float* xr2 = bufA + (size_t)n * 16;                // n*32 f32 (after n*32 bf16)
  float* h2  = bufB;                                 // n*32 f32
  float* gate = bufB + (size_t)n * 32;               // n f32
  unsigned* scratch = (unsigned*)bufC;    // E u32, dead before gat1 writes hbuf
  int* ip       = (int*)(bufC + nf64);
  int* row_ptr  = ip;  ip += (n + 2);
  int* buk_cnt  = ip;  ip += 512;
  int* sbuk_off = ip;  ip += 520;
  int* buk_run  = ip;  ip += 512;
  int* csr_src  = ip;  ip += Etot;        // E + n ints
  unsigned short* WT1 = (unsigned short*)ip;         // 128*128 bf16
  unsigned short* WT2 = WT1 + 128 * 128;             // 64*64 bf16
  float* ppart = (float*)(WT2 + 64 * 64);            // 256*33 f32 pool partials

  hipMemsetAsync(buk_cnt, 0, 512 * sizeof(int), stream);

  int mb64 = (n + 63) / 64;   // 64-row GEMM tiles

  wtrans_kernel<<<11, 256, 0, stream>>>(Wl1, Wr1, WT1, Wl2, Wr2, WT2);

  mm_mfma_kernel<128, 64, 8><<<mb64, 512, 0, stream>>>(x, WT1, bl1, br1, xl1, xr1, n);

  bucket_hist_kernel<<<256, 256, 0, stream>>>(ei, buk_cnt, E, nbuk);
  scan_buckets_kernel<<<1, 512, 0, stream>>>(buk_cnt, sbuk_off, buk_run, nbuk, E);
  partition_kernel<<<256, 256, 0, stream>>>(ei, buk_run, scratch, E, nbuk);
  bucket_fill_kernel<<<nbuk, 256, 0, stream>>>(scratch, sbuk_off, row_ptr, csr_src, n, nbuk);

  int gatblocks = (n + 3) / 4;   // 4 waves (dsts) per block
  gat1_kernel<<<gatblocks, 256, 0, stream>>>(xl1, xr1, row_ptr, csr_src, att1, bias1, hbuf, n);

  mm_mfma_kernel<64, 32, 4><<<mb64, 256, 0, stream>>>(hbuf, WT2, bl2, br2, xl2, xr2, n);

  gat2_kernel<<<gatblocks, 256, 0, stream>>>(xl2, xr2, row_ptr, csr_src, att2, bias2, h2, n);

  gate_kernel<<<(n + 255) / 256, 256, 0, stream>>>(h2, Wg1, bg1, Wg2, bg2, gate, n);

  pool_partial_kernel<<<256, 256, 0, stream>>>(h2, gate, batch, ppart, n);
  pool_final_kernel<<<64, 64, 0, stream>>>(ppart, W1, b1, W2, b2, out);
}